// Round 7
// baseline (271.273 us; speedup 1.0000x reference)
//
#include <hip/hip_runtime.h>
#include <hip/hip_bf16.h>

// out[b,e] = m[c,e] + sum_d z[b,d] * L[c,e,d],  c = components[b]
// v7: kill the per-iteration vmcnt(0) barrier drain (v6: ~3300 cyc/iter vs
// ~150 cyc issue work = 95% stall). Depth-3 LDS ring with raw s_barrier +
// counted s_waitcnt vmcnt(8): stages it+1,it+2 stay in flight across
// barriers (T3/T4, m201-proven pattern). Counted vmcnt requires uniform
// loads/thread/stage -> zb tiles padded 10240->12288 B (768 chunks) so every
// thread issues exactly 3 A-loads + 1 B-load per stage. Pad chunks are
// DMA'd into LDS but never read. Last two iterations peel vmcnt(4)/vmcnt(0).
// build_map / zgather / fragment maps / epilogue unchanged from v6 (proven).

#define DDIM  2048
#define BSAMP 1024
#define KCOMP 10
#define MPAD  160                      // max n_k pad; Binom(1024,0.1)+6sigma
#define NT    32                       // block N tile
#define BK    32                       // d-elems per iteration
#define NITER (DDIM / BK)              // 64
#define TILEP 12288                    // padded zb tile stride (768 chunks)
#define ABYTES 12288                   // A LDS region (640 real + 128 pad)
#define BBYTES 4096                    // fp32 B stage
#define STAGE_BYTES (ABYTES + BBYTES)  // 16384
#define NBUF  3                        // 49152 B LDS -> 3 blocks/CU

typedef __attribute__((ext_vector_type(8))) short bf16x8;  // 8 bf16 = 4 VGPRs
typedef __attribute__((ext_vector_type(4))) float f32x4;

__device__ __forceinline__ void async16(void* lds, const void* g) {
    __builtin_amdgcn_global_load_lds(
        (const __attribute__((address_space(1))) void*)g,
        (__attribute__((address_space(3))) void*)lds, 16, 0, 0);
}

__device__ __forceinline__ short bfs(float x) {
    __hip_bfloat16 h = __float2bfloat16(x);   // RNE
    return *reinterpret_cast<short*>(&h);
}

// Kernel 1: counting-bucket the 1024 samples by component (proven v1-v6).
__global__ void build_map(const int* __restrict__ comp,
                          int* __restrict__ rowmap,
                          int* __restrict__ counts) {
    __shared__ int sc[KCOMP];
    const int t = threadIdx.x;
    if (t < KCOMP) sc[t] = 0;
    __syncthreads();
    const int c = comp[t];
    const int r = atomicAdd(&sc[c], 1);
    if (r < MPAD) rowmap[c * MPAD + r] = t;
    __syncthreads();
    if (t < KCOMP) counts[t] = sc[t];
}

// Kernel 2: build the tiled zb image (proven v6; tile stride now TILEP).
// Block (k, sp) converts slot pair {2sp, 2sp+1}. Thread t, pass p handles
// tile it = p*32 + (t>>3), chunk c = t&7: 8 fp32 of z row (2sp + (c>>2)) at
// d = it*32 + (c&3)*8 -> 16B bf16 at tile + sp*128 + ((c^(sp&7))*16).
__global__ void zgather(const float* __restrict__ z,
                        const int* __restrict__ rowmap,
                        short* __restrict__ zb) {
    const int k  = blockIdx.x;
    const int sp = blockIdx.y;                  // slot pair / macro-row
    const int t  = threadIdx.x;
    const int c  = t & 7;                       // chunk within macro-row
    const int g  = c & 3;
    const int s0 = rowmap[k * MPAD + 2 * sp]     & (BSAMP - 1);
    const int s1 = rowmap[k * MPAD + 2 * sp + 1] & (BSAMP - 1);
    const int src = (c >> 2) ? s1 : s0;
    const int swz = (c ^ (sp & 7)) * 16;        // byte offset within 128B
    char* kbase = (char*)zb + (size_t)k * NITER * TILEP + sp * 128 + swz;
#pragma unroll
    for (int p = 0; p < 2; ++p) {
        const int it = p * 32 + (t >> 3);
        const float* zr = z + (size_t)src * DDIM + it * BK + g * 8;
        f32x4 x = *(const f32x4*)zr;
        f32x4 y = *(const f32x4*)(zr + 4);
        bf16x8 r;
#pragma unroll
        for (int i = 0; i < 4; ++i) { r[i] = bfs(x[i]); r[4 + i] = bfs(y[i]); }
        *(bf16x8*)(kbase + (size_t)it * TILEP) = r;
    }
}

// Kernel 3: grid = (2048/NT, KCOMP) = 640 blocks, block = 256 (4 waves).
// Block tile 160x32; wave tile 80x16. acc[5]. Depth-3 ring pipeline:
//   stage(0,1,2); loop: waitcnt vmcnt(8) -> barrier -> compute buf ->
//   barrier -> stage(it+3). vmcnt(8) = 2 stages x 4 loads/thread in flight.
// LDS A: linear copy of zb tile; frag addr = (mh*40+frh)*128 +
//   ((fra^frh)*16) + mt*1024 (swizzle baked into zb image; conflict-free).
// LDS B: 32 rows x 128B, chunk h = g ^ (r&7) via pre-swizzled global col.
__global__ __launch_bounds__(256, 3)
void gmm_gemm(const short* __restrict__ zb,
              const float* __restrict__ mvec,
              const float* __restrict__ Lmat,
              const int* __restrict__ rowmap,
              const int* __restrict__ counts,
              float* __restrict__ out) {
    __shared__ __attribute__((aligned(16))) char smem[NBUF * STAGE_BYTES];
    const int t    = threadIdx.x;
    const int lane = t & 63;
    const int w    = t >> 6;
    const int mh   = w >> 1;          // wave M-half (80 rows)
    const int nh   = w & 1;           // wave N-half (16 cols)
    const int k    = blockIdx.y;
    const int n0   = blockIdx.x * NT;
    const float* Lk = Lmat + (size_t)k * DDIM * DDIM;
    const char* zt  = (const char*)zb + (size_t)k * NITER * TILEP;
    const int cnt  = counts[k];

    // count-aware trim: this wave's rows are mh*80 + mt*16 + {0..15}
    int mtmax = (cnt - mh * 80 + 15) >> 4;
    mtmax = mtmax < 0 ? 0 : (mtmax > 5 ? 5 : mtmax);

    // B staging: 256 chunks (row = t>>3, h = t&7), pre-swizzled source col
    const int br = t >> 3,          bc = ((t & 7) ^ (br & 7)) * 4;
    const unsigned ub = (unsigned)(t & ~63) * 16;   // wave-uniform byte base

    auto stage = [&](int bi, int it) {              // 4 loads/thread, uniform
        char* lb = smem + bi * STAGE_BYTES;
        const char* at = zt + (size_t)it * TILEP;
        async16(lb + ub,          at + t * 16);
        async16(lb + 4096 + ub,   at + 4096 + t * 16);
        async16(lb + 8192 + ub,   at + 8192 + t * 16);
        async16(lb + ABYTES + ub, Lk + (size_t)(n0 + br) * DDIM + it * BK + bc);
    };

    f32x4 acc[5];
#pragma unroll
    for (int mt = 0; mt < 5; ++mt) acc[mt] = (f32x4){0.f, 0.f, 0.f, 0.f};

    const int fr = lane & 15;        // frag row
    const int g  = lane >> 4;        // k-group (8 elems) of this lane
    const int rb = nh * 16 + fr;     // B row (block-relative e)
    const int h0 = ((2 * g)     ^ (rb & 7)) * 4;
    const int h1 = ((2 * g + 1) ^ (rb & 7)) * 4;
    const int frh = fr >> 1;
    const int fra = (fr & 1) * 4 + g;
    const int abase = (mh * 40 + frh) * 128 + ((fra ^ frh) * 16);

    auto compute = [&](int bi) {
        const char* lb = smem + bi * STAGE_BYTES;
        const float* B = (const float*)(lb + ABYTES);
        f32x4 x = *(const f32x4*)(B + rb * 32 + h0);
        f32x4 y = *(const f32x4*)(B + rb * 32 + h1);
        bf16x8 bb;
#pragma unroll
        for (int i = 0; i < 4; ++i) { bb[i] = bfs(x[i]); bb[4 + i] = bfs(y[i]); }
#pragma unroll
        for (int mt = 0; mt < 5; ++mt) {
            if (mt < mtmax) {        // wave-uniform guard, static acc index
                bf16x8 a = *(const bf16x8*)(lb + abase + mt * 1024);
                acc[mt] = __builtin_amdgcn_mfma_f32_16x16x32_bf16(a, bb, acc[mt], 0, 0, 0);
            }
        }
    };

    stage(0, 0); stage(1, 1); stage(2, 2);          // 12 loads/thread in flight
    int bi = 0;
    for (int it = 0; it < NITER - 2; ++it) {
        asm volatile("s_waitcnt vmcnt(8)" ::: "memory");  // stage(it) landed
        __builtin_amdgcn_s_barrier();                     // buf bi full, all waves
        compute(bi);
        __builtin_amdgcn_s_barrier();                     // buf bi consumed
        if (it + 3 < NITER) stage(bi, it + 3);
        bi = (bi == NBUF - 1) ? 0 : bi + 1;
    }
    // it = NITER-2: only stage(NITER-1) outstanding after wait
    asm volatile("s_waitcnt vmcnt(4)" ::: "memory");
    __builtin_amdgcn_s_barrier();
    compute(bi);
    __builtin_amdgcn_s_barrier();
    bi = (bi == NBUF - 1) ? 0 : bi + 1;
    // it = NITER-1: drain all
    asm volatile("s_waitcnt vmcnt(0)" ::: "memory");
    __builtin_amdgcn_s_barrier();
    compute(bi);

    // epilogue: C/D layout col=lane&15, row=(lane>>4)*4+reg (m89-verified)
    const int rquad = g * 4;
    const int e  = n0 + nh * 16 + fr;
    const float mu = mvec[k * DDIM + e];
#pragma unroll
    for (int mt = 0; mt < 5; ++mt) {
        if (mt < mtmax) {
            const int sb = mh * 80 + mt * 16 + rquad;
#pragma unroll
            for (int r = 0; r < 4; ++r) {
                const int slot = sb + r;
                if (slot < cnt) {
                    const int b = rowmap[k * MPAD + slot];
                    out[(size_t)b * DDIM + e] = acc[mt][r] + mu;
                }
            }
        }
    }
}

extern "C" void kernel_launch(void* const* d_in, const int* in_sizes, int n_in,
                              void* d_out, int out_size, void* d_ws, size_t ws_size,
                              hipStream_t stream) {
    const float* z    = (const float*)d_in[0];
    const float* mvec = (const float*)d_in[1];
    const float* Lmat = (const float*)d_in[2];
    const int* comp   = (const int*)d_in[3];
    float* out        = (float*)d_out;

    int* rowmap = (int*)d_ws;                         // K*MPAD ints = 6400 B
    int* counts = rowmap + KCOMP * MPAD;              // K ints
    short* zb   = (short*)((char*)d_ws + 8192);       // 7.87 MB padded image

    build_map<<<1, BSAMP, 0, stream>>>(comp, rowmap, counts);
    zgather<<<dim3(KCOMP, MPAD / 2), 256, 0, stream>>>(z, rowmap, zb);
    gmm_gemm<<<dim3(DDIM / NT, KCOMP), 256, 0, stream>>>(zb, mvec, Lmat,
                                                         rowmap, counts, out);
}